// Round 14
// baseline (259.817 us; speedup 1.0000x reference)
//
#include <hip/hip_runtime.h>
#include <hip/hip_bf16.h>

#define IN_FEATS 256
#define ENC_H    20
#define DEC_H    64
#define EPB      8192    // edges per binning block

#define NT_LOAD(x)     __builtin_nontemporal_load(&(x))
#define NT_STORE(x, v) __builtin_nontemporal_store((v), &(x))

// ---------------- threefry2x32 (JAX-compatible) ----------------
__device__ __forceinline__ unsigned int rotl32(unsigned int x, int d) {
  return (x << d) | (x >> (32 - d));
}

__device__ __forceinline__ void threefry2x32(unsigned int k0, unsigned int k1,
                                             unsigned int x0, unsigned int x1,
                                             unsigned int& o0, unsigned int& o1) {
  unsigned int ks0 = k0, ks1 = k1, ks2 = k0 ^ k1 ^ 0x1BD11BDAu;
  x0 += ks0; x1 += ks1;
  x0 += x1; x1 = rotl32(x1, 13); x1 ^= x0;
  x0 += x1; x1 = rotl32(x1, 15); x1 ^= x0;
  x0 += x1; x1 = rotl32(x1, 26); x1 ^= x0;
  x0 += x1; x1 = rotl32(x1,  6); x1 ^= x0;
  x0 += ks1; x1 += ks2 + 1u;
  x0 += x1; x1 = rotl32(x1, 17); x1 ^= x0;
  x0 += x1; x1 = rotl32(x1, 29); x1 ^= x0;
  x0 += x1; x1 = rotl32(x1, 16); x1 ^= x0;
  x0 += x1; x1 = rotl32(x1, 24); x1 ^= x0;
  x0 += ks2; x1 += ks0 + 2u;
  x0 += x1; x1 = rotl32(x1, 13); x1 ^= x0;
  x0 += x1; x1 = rotl32(x1, 15); x1 ^= x0;
  x0 += x1; x1 = rotl32(x1, 26); x1 ^= x0;
  x0 += x1; x1 = rotl32(x1,  6); x1 ^= x0;
  x0 += ks0; x1 += ks1 + 3u;
  x0 += x1; x1 = rotl32(x1, 17); x1 ^= x0;
  x0 += x1; x1 = rotl32(x1, 29); x1 ^= x0;
  x0 += x1; x1 = rotl32(x1, 16); x1 ^= x0;
  x0 += x1; x1 = rotl32(x1, 24); x1 ^= x0;
  x0 += ks1; x1 += ks2 + 4u;
  x0 += x1; x1 = rotl32(x1, 13); x1 ^= x0;
  x0 += x1; x1 = rotl32(x1, 15); x1 ^= x0;
  x0 += x1; x1 = rotl32(x1, 26); x1 ^= x0;
  x0 += x1; x1 = rotl32(x1,  6); x1 ^= x0;
  x0 += ks2; x1 += ks0 + 5u;
  o0 = x0; o1 = x1;
}

__device__ __forceinline__ float2 bf2_unpack(unsigned int u) {
  float2 f;
  f.x = __uint_as_float(u << 16);
  f.y = __uint_as_float(u & 0xffff0000u);
  return f;
}

__device__ __forceinline__ unsigned short bf16_bits(float f) {
  __hip_bfloat16 h = __float2bfloat16(f);
  return *reinterpret_cast<unsigned short*>(&h);
}

// ---------------- binning + sort (no global atomics anywhere) ----------------

// per-(block,bin) histogram of col>>8
__global__ __launch_bounds__(1024) void k_binhist(const int* __restrict__ col,
                                                  int* __restrict__ bbc, int E, int nbins) {
  __shared__ int h[256];
  int t = threadIdx.x;
  if (t < 256) h[t] = 0;
  __syncthreads();
  int lo = blockIdx.x * EPB;
  int hi = min(lo + EPB, E);
  for (int e = lo + t; e < hi; e += 1024) atomicAdd(&h[NT_LOAD(col[e]) >> 8], 1);
  __syncthreads();
  if (t < nbins) bbc[blockIdx.x * nbins + t] = h[t];
}

// colA: per-bin scan over the block axis (parallel across blocks' counts)
__global__ void k_colA(const int* __restrict__ bbc, int* __restrict__ base,
                       int* __restrict__ binTot, int nblk, int nbins) {
  __shared__ int sd[256];
  int t = threadIdx.x;
  int bin = blockIdx.x;
  int v = (t < nblk) ? bbc[(size_t)t * nbins + bin] : 0;
  sd[t] = v;
  __syncthreads();
#pragma unroll
  for (int off = 1; off < 256; off <<= 1) {
    int tmp = (t >= off) ? sd[t - off] : 0;
    __syncthreads();
    sd[t] += tmp;
    __syncthreads();
  }
  if (t < nblk) base[(size_t)t * nbins + bin] = sd[t] - v;  // exclusive, bin-local
  if (t == 255) binTot[bin] = sd[255];
}

// colB: single block scans <=256 bin totals -> binStart[nbins+1]
__global__ void k_colB(const int* __restrict__ binTot, int* __restrict__ binStart, int nbins) {
  __shared__ int sd[256];
  int t = threadIdx.x;
  int v = (t < nbins) ? binTot[t] : 0;
  sd[t] = v;
  __syncthreads();
#pragma unroll
  for (int off = 1; off < 256; off <<= 1) {
    int tmp = (t >= off) ? sd[t - off] : 0;
    __syncthreads();
    sd[t] += tmp;
    __syncthreads();
  }
  if (t < nbins) {
    binStart[t] = sd[t] - v;
    if (t == nbins - 1) binStart[nbins] = sd[t];
  }
}

// scatter edges into bins: binned[slot] = r | c<<16 ; einv[e] = slot (coalesced)
__global__ __launch_bounds__(1024) void k_binscatter(const int* __restrict__ row,
                                                     const int* __restrict__ col,
                                                     const int* __restrict__ base,
                                                     const int* __restrict__ binStart,
                                                     unsigned int* __restrict__ binned,
                                                     int* __restrict__ einv,
                                                     int E, int nbins) {
  __shared__ int cur[256];
  int t = threadIdx.x;
  if (t < nbins) cur[t] = binStart[t] + base[(size_t)blockIdx.x * nbins + t];
  __syncthreads();
  int lo = blockIdx.x * EPB;
  int hi = min(lo + EPB, E);
  for (int e = lo + t; e < hi; e += 1024) {
    int c = NT_LOAD(col[e]);
    int r = NT_LOAD(row[e]);
    int slot = atomicAdd(&cur[c >> 8], 1);
    NT_STORE(binned[slot], (unsigned int)r | ((unsigned int)c << 16));
    NT_STORE(einv[e], slot);
  }
}

// per-bin counting sort by node: emits sorted_r[] (u16), nstart[N+1], dinv[N]
__global__ __launch_bounds__(1024) void k_binsort(const unsigned int* __restrict__ binned,
                                                  const int* __restrict__ binStart,
                                                  unsigned short* __restrict__ sorted_r,
                                                  int* __restrict__ nstart,
                                                  float* __restrict__ dinv,
                                                  int N, int E) {
  __shared__ int cnt[256];
  __shared__ int ls[256];
  __shared__ int cur[256];
  int t = threadIdx.x;
  int bin = blockIdx.x;
  if (t < 256) cnt[t] = 0;
  __syncthreads();
  int s = binStart[bin], epos = binStart[bin + 1];
  for (int i = s + t; i < epos; i += 1024)
    atomicAdd(&cnt[(NT_LOAD(binned[i]) >> 16) & 0xFFu], 1);
  __syncthreads();
  int v = (t < 256) ? cnt[t] : 0;
  if (t < 256) ls[t] = v;
  __syncthreads();
#pragma unroll
  for (int off = 1; off < 256; off <<= 1) {
    int tmp = 0;
    if (t < 256 && t >= off) tmp = ls[t - off];
    __syncthreads();
    if (t < 256 && t >= off) ls[t] += tmp;
    __syncthreads();
  }
  if (t < 256) {
    int ex = ls[t] - v;      // exclusive prefix within bin
    cur[t] = s + ex;
    int n = (bin << 8) + t;
    if (n < N) {
      nstart[n] = s + ex;
      dinv[n] = rsqrtf((float)(v + 1));
    }
  }
  if (bin == 0 && t == 0) nstart[N] = E;
  __syncthreads();
  for (int i = s + t; i < epos; i += 1024) {
    unsigned int e32 = NT_LOAD(binned[i]);
    int cl = (int)((e32 >> 16) & 0xFFu);
    int slot = atomicAdd(&cur[cl], 1);
    NT_STORE(sorted_r[slot], (unsigned short)(e32 & 0xFFFFu));
  }
}

// ---------------- dense kernels ----------------

// xwd[n] = bf16((x[n] @ W_gcn) * dinv[n]); 4 threads/node, interleaved float4 access
__global__ void k_xw(const float* __restrict__ x, const float* __restrict__ W,
                     const float* __restrict__ dinv, __hip_bfloat16* __restrict__ xwd, int N) {
  __shared__ float Wl[IN_FEATS * ENC_H];
  for (int i = threadIdx.x; i < IN_FEATS * ENC_H; i += blockDim.x) Wl[i] = W[i];
  __syncthreads();
  int g = blockIdx.x * blockDim.x + threadIdx.x;
  int n = g >> 2, part = g & 3;
  if (n >= N) return;
  float acc[ENC_H];
#pragma unroll
  for (int j = 0; j < ENC_H; j++) acc[j] = 0.0f;
  const float4* x4 = reinterpret_cast<const float4*>(x + (size_t)n * IN_FEATS);
#pragma unroll 4
  for (int k4 = 0; k4 < 16; k4++) {
    float4 v = x4[k4 * 4 + part];
    int kbase = k4 * 16 + part * 4;
    const float* w0 = &Wl[(kbase + 0) * ENC_H];
    const float* w1 = &Wl[(kbase + 1) * ENC_H];
    const float* w2 = &Wl[(kbase + 2) * ENC_H];
    const float* w3 = &Wl[(kbase + 3) * ENC_H];
#pragma unroll
    for (int j = 0; j < ENC_H; j++) {
      acc[j] = fmaf(v.x, w0[j], acc[j]);
      acc[j] = fmaf(v.y, w1[j], acc[j]);
      acc[j] = fmaf(v.z, w2[j], acc[j]);
      acc[j] = fmaf(v.w, w3[j], acc[j]);
    }
  }
#pragma unroll
  for (int j = 0; j < ENC_H; j++) acc[j] += __shfl_xor(acc[j], 1);
#pragma unroll
  for (int j = 0; j < ENC_H; j++) acc[j] += __shfl_xor(acc[j], 2);
  float d = dinv[n];
  __hip_bfloat16* o = xwd + (size_t)n * ENC_H;
  int jb = part * 5;
#pragma unroll
  for (int jj = 0; jj < 5; jj++) o[jb + jj] = __float2bfloat16(acc[jb + jj] * d);
}

// enc: 5 lanes/node, each lane owns 4 feats, uint2 (4 bf16) per neighbor
__global__ void k_gather(const int* __restrict__ nstart,
                         const unsigned short* __restrict__ sorted_r,
                         const __hip_bfloat16* __restrict__ xwd, const float* __restrict__ dinv,
                         const float* __restrict__ bg, float* __restrict__ enc, int N) {
  int t = blockIdx.x * blockDim.x + threadIdx.x;
  int n = t / 5;
  int lane5 = t - n * 5;
  if (n >= N) return;
  int jb = lane5 * 4;
  const char* xwb = (const char*)xwd;
  // self loop
  uint2 sv = *reinterpret_cast<const uint2*>(xwb + (size_t)n * 40 + lane5 * 8);
  float2 a01 = bf2_unpack(sv.x), a23 = bf2_unpack(sv.y);
  float f0 = a01.x, f1 = a01.y, f2 = a23.x, f3 = a23.y;
  int s = nstart[n], epos = nstart[n + 1];
  for (int k = s; k < epos; k++) {
    int r = (int)NT_LOAD(sorted_r[k]);
    uint2 v = *reinterpret_cast<const uint2*>(xwb + (size_t)r * 40 + lane5 * 8);
    float2 b01 = bf2_unpack(v.x), b23 = bf2_unpack(v.y);
    f0 += b01.x; f1 += b01.y; f2 += b23.x; f3 += b23.y;
  }
  float d = dinv[n];
  float4 o;
  o.x = fmaxf(f0 * d + bg[jb + 0], 0.0f);
  o.y = fmaxf(f1 * d + bg[jb + 1], 0.0f);
  o.z = fmaxf(f2 * d + bg[jb + 2], 0.0f);
  o.w = fmaxf(f3 * d + bg[jb + 3], 0.0f);
  *reinterpret_cast<float4*>(enc + (size_t)n * ENC_H + jb) = o;
}

// P/Q split in j-halves: P1=cols0..31 of enc@W1[0:20], P2=cols32..63; same for Q (W1[20:40])
__global__ void k_pq(const float* __restrict__ enc, const float* __restrict__ W1,
                     __hip_bfloat16* __restrict__ P1, __hip_bfloat16* __restrict__ P2,
                     __hip_bfloat16* __restrict__ Q1, __hip_bfloat16* __restrict__ Q2, int N) {
  __shared__ float Wl[2 * ENC_H * DEC_H];
  for (int i = threadIdx.x; i < 2 * ENC_H * DEC_H; i += blockDim.x) Wl[i] = W1[i];
  __syncthreads();
  int t = blockIdx.x * blockDim.x + threadIdx.x;
  int n = t / DEC_H, j = t % DEC_H;
  if (n >= N) return;
  const float* en = enc + (size_t)n * ENC_H;
  float p = 0.0f, q = 0.0f;
#pragma unroll
  for (int k = 0; k < ENC_H; k++) {
    float ev = en[k];
    p = fmaf(ev, Wl[k * DEC_H + j], p);
    q = fmaf(ev, Wl[(k + ENC_H) * DEC_H + j], q);
  }
  size_t idx = (size_t)n * 32 + (j & 31);
  if (j < 32) { P1[idx] = __float2bfloat16(p); Q1[idx] = __float2bfloat16(q); }
  else        { P2[idx] = __float2bfloat16(p); Q2[idx] = __float2bfloat16(q); }
}

// t3 = enc[node_id] @ W1[40:60] + b1
__global__ void k_t3(const float* __restrict__ enc, const float* __restrict__ W1,
                     const float* __restrict__ b1, const int* __restrict__ node_id,
                     float* __restrict__ t3) {
  int j = threadIdx.x;
  int nid = node_id[0];
  const float* en = enc + (size_t)nid * ENC_H;
  float a = b1[j];
#pragma unroll
  for (int k = 0; k < ENC_H; k++) a = fmaf(en[k], W1[(2 * ENC_H + k) * DEC_H + j], a);
  t3[j] = a;
}

// decoder half-pass: HALF=0 writes bf16 partial; HALF=1 accumulates and writes bf16 od
template <int HALF>
__global__ void k_dec_half(const unsigned int* __restrict__ binned,
                           const __hip_bfloat16* __restrict__ Ph,
                           const __hip_bfloat16* __restrict__ Qh,
                           const float* __restrict__ t3, const float* __restrict__ W2,
                           const float* __restrict__ b2,
                           unsigned short* __restrict__ partial, int E) {
  __shared__ float t3l[32], w2l[32];
  if (threadIdx.x < 32) {
    t3l[threadIdx.x] = t3[HALF * 32 + threadIdx.x];
    w2l[threadIdx.x] = W2[HALF * 32 + threadIdx.x];
  }
  __syncthreads();
  int pos = blockIdx.x * blockDim.x + threadIdx.x;
  if (pos >= E) return;
  unsigned int v = NT_LOAD(binned[pos]);
  int r = (int)(v & 0xFFFFu);
  int c = (int)(v >> 16);
  const uint4* pr = reinterpret_cast<const uint4*>(Ph + (size_t)r * 32);  // 64B row
  const uint4* qc = reinterpret_cast<const uint4*>(Qh + (size_t)c * 32);
  float acc = 0.0f;
#pragma unroll
  for (int b = 0; b < 4; b++) {  // 8 bf16 per uint4
    uint4 pu = pr[b];
    uint4 qu = qc[b];
    int j0 = b * 8;
    float2 p0 = bf2_unpack(pu.x), q0 = bf2_unpack(qu.x);
    float2 p1 = bf2_unpack(pu.y), q1 = bf2_unpack(qu.y);
    float2 p2 = bf2_unpack(pu.z), q2 = bf2_unpack(qu.z);
    float2 p3 = bf2_unpack(pu.w), q3 = bf2_unpack(qu.w);
    float h;
    h = fmaxf(p0.x + q0.x + t3l[j0 + 0], 0.0f); acc = fmaf(h, w2l[j0 + 0], acc);
    h = fmaxf(p0.y + q0.y + t3l[j0 + 1], 0.0f); acc = fmaf(h, w2l[j0 + 1], acc);
    h = fmaxf(p1.x + q1.x + t3l[j0 + 2], 0.0f); acc = fmaf(h, w2l[j0 + 2], acc);
    h = fmaxf(p1.y + q1.y + t3l[j0 + 3], 0.0f); acc = fmaf(h, w2l[j0 + 3], acc);
    h = fmaxf(p2.x + q2.x + t3l[j0 + 4], 0.0f); acc = fmaf(h, w2l[j0 + 4], acc);
    h = fmaxf(p2.y + q2.y + t3l[j0 + 5], 0.0f); acc = fmaf(h, w2l[j0 + 5], acc);
    h = fmaxf(p3.x + q3.x + t3l[j0 + 6], 0.0f); acc = fmaf(h, w2l[j0 + 6], acc);
    h = fmaxf(p3.y + q3.y + t3l[j0 + 7], 0.0f); acc = fmaf(h, w2l[j0 + 7], acc);
  }
  if (HALF == 0) {
    NT_STORE(partial[pos], bf16_bits(acc));
  } else {
    float prev = __uint_as_float((unsigned int)NT_LOAD(partial[pos]) << 16);
    float od = acc + prev + b2[0];
    NT_STORE(partial[pos], bf16_bits(od));
  }
}

// final: e in order -> od gather from L2-resident bf16 partial, gumbel-sigmoid, sequential out
__global__ void k_final(const int* __restrict__ einv, const unsigned short* __restrict__ partial,
                        float* __restrict__ out, int E) {
  int e = blockIdx.x * blockDim.x + threadIdx.x;
  if (e >= E) return;
  float od = __uint_as_float((unsigned int)partial[NT_LOAD(einv[e])] << 16);
  unsigned int o0, o1;
  threefry2x32(0u, 123u, 0u, (unsigned int)e, o0, o1);
  unsigned int bits = o0 ^ o1;
  float u = __uint_as_float((bits >> 9) | 0x3f800000u) - 1.0f;
  float eps = (-0.9998f) * u + 0.9999f;
  float gate = logf(eps) - log1pf(-eps);
  float s = 1.0f / (1.0f + expf(-(gate + od)));
  NT_STORE(out[e], s);
}

// ---------------- launch ----------------
extern "C" void kernel_launch(void* const* d_in, const int* in_sizes, int n_in,
                              void* d_out, int out_size, void* d_ws, size_t ws_size,
                              hipStream_t stream) {
  const float* x       = (const float*)d_in[0];
  const int*   edge    = (const int*)d_in[1];
  const int*   node_id = (const int*)d_in[2];
  const float* W_gcn   = (const float*)d_in[3];
  const float* b_gcn   = (const float*)d_in[4];
  const float* W1      = (const float*)d_in[5];
  const float* b1      = (const float*)d_in[6];
  const float* W2      = (const float*)d_in[7];
  const float* b2      = (const float*)d_in[8];
  float* out = (float*)d_out;

  int N = in_sizes[0] / IN_FEATS;
  int E = in_sizes[1] / 2;
  const int* erow = edge;
  const int* ecol = edge + E;
  int nbins = (N + 255) >> 8;           // 196 for N=50000 (<=256 required)
  int NB = (E + EPB - 1) / EPB;         // 196 binning blocks (<=256 required)

  char* ws = (char*)d_ws;
  size_t off = 0;
  auto alloc = [&](size_t bytes) {
    char* p = ws + off;
    off = (off + bytes + 255) & ~(size_t)255;
    return p;
  };
  __hip_bfloat16* xwd = (__hip_bfloat16*)alloc((size_t)N * ENC_H * sizeof(__hip_bfloat16));
  float* enc  = (float*)alloc((size_t)N * ENC_H * sizeof(float));
  float* dinv = (float*)alloc((size_t)N * sizeof(float));
  int*  nstart = (int*)alloc((size_t)(N + 1) * sizeof(int));
  unsigned int*   binned   = (unsigned int*)alloc((size_t)E * sizeof(unsigned int));
  int*            einv     = (int*)alloc((size_t)E * sizeof(int));
  unsigned short* sorted_r = (unsigned short*)alloc((size_t)E * sizeof(unsigned short));
  int* bbc      = (int*)alloc((size_t)NB * nbins * sizeof(int));
  int* base     = (int*)alloc((size_t)NB * nbins * sizeof(int));
  int* binTot   = (int*)alloc((size_t)nbins * sizeof(int));
  int* binStart = (int*)alloc((size_t)(nbins + 1) * sizeof(int));
  __hip_bfloat16* P1 = (__hip_bfloat16*)alloc((size_t)N * 32 * sizeof(__hip_bfloat16));
  __hip_bfloat16* P2 = (__hip_bfloat16*)alloc((size_t)N * 32 * sizeof(__hip_bfloat16));
  __hip_bfloat16* Q1 = (__hip_bfloat16*)alloc((size_t)N * 32 * sizeof(__hip_bfloat16));
  __hip_bfloat16* Q2 = (__hip_bfloat16*)alloc((size_t)N * 32 * sizeof(__hip_bfloat16));
  unsigned short* partial = (unsigned short*)alloc((size_t)E * sizeof(unsigned short));
  float* t3   = (float*)alloc((size_t)DEC_H * sizeof(float));
  (void)ws_size; (void)n_in; (void)out_size;

  const int B = 256;
  int ge  = (E + B - 1) / B;
  int gxw = (N * 4 + B - 1) / B;
  int gg  = (N * 5 + B - 1) / B;
  int gpq = (N * DEC_H + B - 1) / B;

  k_binhist   <<<NB, 1024, 0, stream>>>(ecol, bbc, E, nbins);
  k_colA      <<<nbins, 256, 0, stream>>>(bbc, base, binTot, NB, nbins);
  k_colB      <<<1, 256, 0, stream>>>(binTot, binStart, nbins);
  k_binscatter<<<NB, 1024, 0, stream>>>(erow, ecol, base, binStart, binned, einv, E, nbins);
  k_binsort   <<<nbins, 1024, 0, stream>>>(binned, binStart, sorted_r, nstart, dinv, N, E);
  k_xw        <<<gxw, B, 0, stream>>>(x, W_gcn, dinv, xwd, N);
  k_gather    <<<gg, B, 0, stream>>>(nstart, sorted_r, xwd, dinv, b_gcn, enc, N);
  k_pq        <<<gpq, B, 0, stream>>>(enc, W1, P1, P2, Q1, Q2, N);
  k_t3        <<<1, DEC_H, 0, stream>>>(enc, W1, b1, node_id, t3);
  k_dec_half<0><<<ge, B, 0, stream>>>(binned, P1, Q1, t3, W2, b2, partial, E);
  k_dec_half<1><<<ge, B, 0, stream>>>(binned, P2, Q2, t3, W2, b2, partial, E);
  k_final     <<<ge, B, 0, stream>>>(einv, partial, out, E);
}

// Round 15
// 172.669 us; speedup vs baseline: 1.5047x; 1.5047x over previous
//
#include <hip/hip_runtime.h>
#include <hip/hip_bf16.h>

#define IN_FEATS 256
#define ENC_H    20
#define DEC_H    64
#define EPB      8192    // edges per binning block

// ---------------- threefry2x32 (JAX-compatible) ----------------
__device__ __forceinline__ unsigned int rotl32(unsigned int x, int d) {
  return (x << d) | (x >> (32 - d));
}

__device__ __forceinline__ void threefry2x32(unsigned int k0, unsigned int k1,
                                             unsigned int x0, unsigned int x1,
                                             unsigned int& o0, unsigned int& o1) {
  unsigned int ks0 = k0, ks1 = k1, ks2 = k0 ^ k1 ^ 0x1BD11BDAu;
  x0 += ks0; x1 += ks1;
  x0 += x1; x1 = rotl32(x1, 13); x1 ^= x0;
  x0 += x1; x1 = rotl32(x1, 15); x1 ^= x0;
  x0 += x1; x1 = rotl32(x1, 26); x1 ^= x0;
  x0 += x1; x1 = rotl32(x1,  6); x1 ^= x0;
  x0 += ks1; x1 += ks2 + 1u;
  x0 += x1; x1 = rotl32(x1, 17); x1 ^= x0;
  x0 += x1; x1 = rotl32(x1, 29); x1 ^= x0;
  x0 += x1; x1 = rotl32(x1, 16); x1 ^= x0;
  x0 += x1; x1 = rotl32(x1, 24); x1 ^= x0;
  x0 += ks2; x1 += ks0 + 2u;
  x0 += x1; x1 = rotl32(x1, 13); x1 ^= x0;
  x0 += x1; x1 = rotl32(x1, 15); x1 ^= x0;
  x0 += x1; x1 = rotl32(x1, 26); x1 ^= x0;
  x0 += x1; x1 = rotl32(x1,  6); x1 ^= x0;
  x0 += ks0; x1 += ks1 + 3u;
  x0 += x1; x1 = rotl32(x1, 17); x1 ^= x0;
  x0 += x1; x1 = rotl32(x1, 29); x1 ^= x0;
  x0 += x1; x1 = rotl32(x1, 16); x1 ^= x0;
  x0 += x1; x1 = rotl32(x1, 24); x1 ^= x0;
  x0 += ks1; x1 += ks2 + 4u;
  x0 += x1; x1 = rotl32(x1, 13); x1 ^= x0;
  x0 += x1; x1 = rotl32(x1, 15); x1 ^= x0;
  x0 += x1; x1 = rotl32(x1, 26); x1 ^= x0;
  x0 += x1; x1 = rotl32(x1,  6); x1 ^= x0;
  x0 += ks2; x1 += ks0 + 5u;
  o0 = x0; o1 = x1;
}

__device__ __forceinline__ float2 bf2_unpack(unsigned int u) {
  float2 f;
  f.x = __uint_as_float(u << 16);
  f.y = __uint_as_float(u & 0xffff0000u);
  return f;
}

// ---------------- binning + sort (no global atomics anywhere) ----------------

// per-(block,bin) histogram of col>>8
__global__ __launch_bounds__(1024) void k_binhist(const int* __restrict__ col,
                                                  int* __restrict__ bbc, int E, int nbins) {
  __shared__ int h[256];
  int t = threadIdx.x;
  if (t < 256) h[t] = 0;
  __syncthreads();
  int lo = blockIdx.x * EPB;
  int hi = min(lo + EPB, E);
  for (int e = lo + t; e < hi; e += 1024) atomicAdd(&h[col[e] >> 8], 1);
  __syncthreads();
  if (t < nbins) bbc[blockIdx.x * nbins + t] = h[t];
}

// colA: per-bin scan over the block axis (parallel across blocks' counts)
__global__ void k_colA(const int* __restrict__ bbc, int* __restrict__ base,
                       int* __restrict__ binTot, int nblk, int nbins) {
  __shared__ int sd[256];
  int t = threadIdx.x;
  int bin = blockIdx.x;
  int v = (t < nblk) ? bbc[(size_t)t * nbins + bin] : 0;
  sd[t] = v;
  __syncthreads();
#pragma unroll
  for (int off = 1; off < 256; off <<= 1) {
    int tmp = (t >= off) ? sd[t - off] : 0;
    __syncthreads();
    sd[t] += tmp;
    __syncthreads();
  }
  if (t < nblk) base[(size_t)t * nbins + bin] = sd[t] - v;  // exclusive, bin-local
  if (t == 255) binTot[bin] = sd[255];
}

// colB: single block scans <=256 bin totals -> binStart[nbins+1]
__global__ void k_colB(const int* __restrict__ binTot, int* __restrict__ binStart, int nbins) {
  __shared__ int sd[256];
  int t = threadIdx.x;
  int v = (t < nbins) ? binTot[t] : 0;
  sd[t] = v;
  __syncthreads();
#pragma unroll
  for (int off = 1; off < 256; off <<= 1) {
    int tmp = (t >= off) ? sd[t - off] : 0;
    __syncthreads();
    sd[t] += tmp;
    __syncthreads();
  }
  if (t < nbins) {
    binStart[t] = sd[t] - v;
    if (t == nbins - 1) binStart[nbins] = sd[t];
  }
}

// scatter edges into bins: binned[slot] = r | c<<16 ; einv[e] = slot (coalesced)
__global__ __launch_bounds__(1024) void k_binscatter(const int* __restrict__ row,
                                                     const int* __restrict__ col,
                                                     const int* __restrict__ base,
                                                     const int* __restrict__ binStart,
                                                     unsigned int* __restrict__ binned,
                                                     int* __restrict__ einv,
                                                     int E, int nbins) {
  __shared__ int cur[256];
  int t = threadIdx.x;
  if (t < nbins) cur[t] = binStart[t] + base[(size_t)blockIdx.x * nbins + t];
  __syncthreads();
  int lo = blockIdx.x * EPB;
  int hi = min(lo + EPB, E);
  for (int e = lo + t; e < hi; e += 1024) {
    int c = col[e];
    int slot = atomicAdd(&cur[c >> 8], 1);
    binned[slot] = (unsigned int)row[e] | ((unsigned int)c << 16);
    einv[e] = slot;
  }
}

// per-bin counting sort by node: emits sorted_r[] (u16), nstart[N+1], dinv[N]
__global__ __launch_bounds__(1024) void k_binsort(const unsigned int* __restrict__ binned,
                                                  const int* __restrict__ binStart,
                                                  unsigned short* __restrict__ sorted_r,
                                                  int* __restrict__ nstart,
                                                  float* __restrict__ dinv,
                                                  int N, int E) {
  __shared__ int cnt[256];
  __shared__ int ls[256];
  __shared__ int cur[256];
  int t = threadIdx.x;
  int bin = blockIdx.x;
  if (t < 256) cnt[t] = 0;
  __syncthreads();
  int s = binStart[bin], epos = binStart[bin + 1];
  for (int i = s + t; i < epos; i += 1024)
    atomicAdd(&cnt[(binned[i] >> 16) & 0xFFu], 1);
  __syncthreads();
  int v = (t < 256) ? cnt[t] : 0;
  if (t < 256) ls[t] = v;
  __syncthreads();
#pragma unroll
  for (int off = 1; off < 256; off <<= 1) {
    int tmp = 0;
    if (t < 256 && t >= off) tmp = ls[t - off];
    __syncthreads();
    if (t < 256 && t >= off) ls[t] += tmp;
    __syncthreads();
  }
  if (t < 256) {
    int ex = ls[t] - v;      // exclusive prefix within bin
    cur[t] = s + ex;
    int n = (bin << 8) + t;
    if (n < N) {
      nstart[n] = s + ex;
      dinv[n] = rsqrtf((float)(v + 1));
    }
  }
  if (bin == 0 && t == 0) nstart[N] = E;
  __syncthreads();
  for (int i = s + t; i < epos; i += 1024) {
    unsigned int e32 = binned[i];
    int cl = (int)((e32 >> 16) & 0xFFu);
    int slot = atomicAdd(&cur[cl], 1);
    sorted_r[slot] = (unsigned short)(e32 & 0xFFFFu);
  }
}

// ---------------- dense kernels ----------------

// xwd[n] = bf16((x[n] @ W_gcn) * dinv[n]); 4 threads/node, interleaved float4 access
__global__ void k_xw(const float* __restrict__ x, const float* __restrict__ W,
                     const float* __restrict__ dinv, __hip_bfloat16* __restrict__ xwd, int N) {
  __shared__ float Wl[IN_FEATS * ENC_H];
  for (int i = threadIdx.x; i < IN_FEATS * ENC_H; i += blockDim.x) Wl[i] = W[i];
  __syncthreads();
  int g = blockIdx.x * blockDim.x + threadIdx.x;
  int n = g >> 2, part = g & 3;
  if (n >= N) return;
  float acc[ENC_H];
#pragma unroll
  for (int j = 0; j < ENC_H; j++) acc[j] = 0.0f;
  const float4* x4 = reinterpret_cast<const float4*>(x + (size_t)n * IN_FEATS);
#pragma unroll 4
  for (int k4 = 0; k4 < 16; k4++) {
    float4 v = x4[k4 * 4 + part];
    int kbase = k4 * 16 + part * 4;
    const float* w0 = &Wl[(kbase + 0) * ENC_H];
    const float* w1 = &Wl[(kbase + 1) * ENC_H];
    const float* w2 = &Wl[(kbase + 2) * ENC_H];
    const float* w3 = &Wl[(kbase + 3) * ENC_H];
#pragma unroll
    for (int j = 0; j < ENC_H; j++) {
      acc[j] = fmaf(v.x, w0[j], acc[j]);
      acc[j] = fmaf(v.y, w1[j], acc[j]);
      acc[j] = fmaf(v.z, w2[j], acc[j]);
      acc[j] = fmaf(v.w, w3[j], acc[j]);
    }
  }
#pragma unroll
  for (int j = 0; j < ENC_H; j++) acc[j] += __shfl_xor(acc[j], 1);
#pragma unroll
  for (int j = 0; j < ENC_H; j++) acc[j] += __shfl_xor(acc[j], 2);
  float d = dinv[n];
  __hip_bfloat16* o = xwd + (size_t)n * ENC_H;
  int jb = part * 5;
#pragma unroll
  for (int jj = 0; jj < 5; jj++) o[jb + jj] = __float2bfloat16(acc[jb + jj] * d);
}

// enc: 5 lanes/node, each lane owns 4 feats, uint2 (4 bf16) per neighbor
__global__ void k_gather(const int* __restrict__ nstart,
                         const unsigned short* __restrict__ sorted_r,
                         const __hip_bfloat16* __restrict__ xwd, const float* __restrict__ dinv,
                         const float* __restrict__ bg, float* __restrict__ enc, int N) {
  int t = blockIdx.x * blockDim.x + threadIdx.x;
  int n = t / 5;
  int lane5 = t - n * 5;
  if (n >= N) return;
  int jb = lane5 * 4;
  const char* xwb = (const char*)xwd;
  // self loop
  uint2 sv = *reinterpret_cast<const uint2*>(xwb + (size_t)n * 40 + lane5 * 8);
  float2 a01 = bf2_unpack(sv.x), a23 = bf2_unpack(sv.y);
  float f0 = a01.x, f1 = a01.y, f2 = a23.x, f3 = a23.y;
  int s = nstart[n], epos = nstart[n + 1];
  for (int k = s; k < epos; k++) {
    int r = (int)sorted_r[k];
    uint2 v = *reinterpret_cast<const uint2*>(xwb + (size_t)r * 40 + lane5 * 8);
    float2 b01 = bf2_unpack(v.x), b23 = bf2_unpack(v.y);
    f0 += b01.x; f1 += b01.y; f2 += b23.x; f3 += b23.y;
  }
  float d = dinv[n];
  float4 o;
  o.x = fmaxf(f0 * d + bg[jb + 0], 0.0f);
  o.y = fmaxf(f1 * d + bg[jb + 1], 0.0f);
  o.z = fmaxf(f2 * d + bg[jb + 2], 0.0f);
  o.w = fmaxf(f3 * d + bg[jb + 3], 0.0f);
  *reinterpret_cast<float4*>(enc + (size_t)n * ENC_H + jb) = o;
}

// P/Q split in j-halves: P1=cols0..31 of enc@W1[0:20], P2=cols32..63; same for Q (W1[20:40])
__global__ void k_pq(const float* __restrict__ enc, const float* __restrict__ W1,
                     __hip_bfloat16* __restrict__ P1, __hip_bfloat16* __restrict__ P2,
                     __hip_bfloat16* __restrict__ Q1, __hip_bfloat16* __restrict__ Q2, int N) {
  __shared__ float Wl[2 * ENC_H * DEC_H];
  for (int i = threadIdx.x; i < 2 * ENC_H * DEC_H; i += blockDim.x) Wl[i] = W1[i];
  __syncthreads();
  int t = blockIdx.x * blockDim.x + threadIdx.x;
  int n = t / DEC_H, j = t % DEC_H;
  if (n >= N) return;
  const float* en = enc + (size_t)n * ENC_H;
  float p = 0.0f, q = 0.0f;
#pragma unroll
  for (int k = 0; k < ENC_H; k++) {
    float ev = en[k];
    p = fmaf(ev, Wl[k * DEC_H + j], p);
    q = fmaf(ev, Wl[(k + ENC_H) * DEC_H + j], q);
  }
  size_t idx = (size_t)n * 32 + (j & 31);
  if (j < 32) { P1[idx] = __float2bfloat16(p); Q1[idx] = __float2bfloat16(q); }
  else        { P2[idx] = __float2bfloat16(p); Q2[idx] = __float2bfloat16(q); }
}

// t3 = enc[node_id] @ W1[40:60] + b1
__global__ void k_t3(const float* __restrict__ enc, const float* __restrict__ W1,
                     const float* __restrict__ b1, const int* __restrict__ node_id,
                     float* __restrict__ t3) {
  int j = threadIdx.x;
  int nid = node_id[0];
  const float* en = enc + (size_t)nid * ENC_H;
  float a = b1[j];
#pragma unroll
  for (int k = 0; k < ENC_H; k++) a = fmaf(en[k], W1[(2 * ENC_H + k) * DEC_H + j], a);
  t3[j] = a;
}

// decoder half-pass: HALF=0 writes bf16 partial; HALF=1 accumulates and writes bf16 od
template <int HALF>
__global__ void k_dec_half(const unsigned int* __restrict__ binned,
                           const __hip_bfloat16* __restrict__ Ph,
                           const __hip_bfloat16* __restrict__ Qh,
                           const float* __restrict__ t3, const float* __restrict__ W2,
                           const float* __restrict__ b2,
                           __hip_bfloat16* __restrict__ partial, int E) {
  __shared__ float t3l[32], w2l[32];
  if (threadIdx.x < 32) {
    t3l[threadIdx.x] = t3[HALF * 32 + threadIdx.x];
    w2l[threadIdx.x] = W2[HALF * 32 + threadIdx.x];
  }
  __syncthreads();
  int pos = blockIdx.x * blockDim.x + threadIdx.x;
  if (pos >= E) return;
  unsigned int v = binned[pos];
  int r = (int)(v & 0xFFFFu);
  int c = (int)(v >> 16);
  const uint4* pr = reinterpret_cast<const uint4*>(Ph + (size_t)r * 32);  // 64B row
  const uint4* qc = reinterpret_cast<const uint4*>(Qh + (size_t)c * 32);
  float acc = 0.0f;
#pragma unroll
  for (int b = 0; b < 4; b++) {  // 8 bf16 per uint4
    uint4 pu = pr[b];
    uint4 qu = qc[b];
    int j0 = b * 8;
    float2 p0 = bf2_unpack(pu.x), q0 = bf2_unpack(qu.x);
    float2 p1 = bf2_unpack(pu.y), q1 = bf2_unpack(qu.y);
    float2 p2 = bf2_unpack(pu.z), q2 = bf2_unpack(qu.z);
    float2 p3 = bf2_unpack(pu.w), q3 = bf2_unpack(qu.w);
    float h;
    h = fmaxf(p0.x + q0.x + t3l[j0 + 0], 0.0f); acc = fmaf(h, w2l[j0 + 0], acc);
    h = fmaxf(p0.y + q0.y + t3l[j0 + 1], 0.0f); acc = fmaf(h, w2l[j0 + 1], acc);
    h = fmaxf(p1.x + q1.x + t3l[j0 + 2], 0.0f); acc = fmaf(h, w2l[j0 + 2], acc);
    h = fmaxf(p1.y + q1.y + t3l[j0 + 3], 0.0f); acc = fmaf(h, w2l[j0 + 3], acc);
    h = fmaxf(p2.x + q2.x + t3l[j0 + 4], 0.0f); acc = fmaf(h, w2l[j0 + 4], acc);
    h = fmaxf(p2.y + q2.y + t3l[j0 + 5], 0.0f); acc = fmaf(h, w2l[j0 + 5], acc);
    h = fmaxf(p3.x + q3.x + t3l[j0 + 6], 0.0f); acc = fmaf(h, w2l[j0 + 6], acc);
    h = fmaxf(p3.y + q3.y + t3l[j0 + 7], 0.0f); acc = fmaf(h, w2l[j0 + 7], acc);
  }
  if (HALF == 0) {
    partial[pos] = __float2bfloat16(acc);
  } else {
    float od = acc + __bfloat162float(partial[pos]) + b2[0];
    partial[pos] = __float2bfloat16(od);  // sequential RMW, coalesced
  }
}

// final: e in order -> od gather from L2-resident bf16 partial, gumbel-sigmoid, sequential out
__global__ void k_final(const int* __restrict__ einv, const __hip_bfloat16* __restrict__ partial,
                        float* __restrict__ out, int E) {
  int e = blockIdx.x * blockDim.x + threadIdx.x;
  if (e >= E) return;
  float od = __bfloat162float(partial[einv[e]]);
  unsigned int o0, o1;
  threefry2x32(0u, 123u, 0u, (unsigned int)e, o0, o1);
  unsigned int bits = o0 ^ o1;
  float u = __uint_as_float((bits >> 9) | 0x3f800000u) - 1.0f;
  float eps = (-0.9998f) * u + 0.9999f;
  float gate = logf(eps) - log1pf(-eps);
  float s = 1.0f / (1.0f + expf(-(gate + od)));
  out[e] = s;
}

// ---------------- launch ----------------
extern "C" void kernel_launch(void* const* d_in, const int* in_sizes, int n_in,
                              void* d_out, int out_size, void* d_ws, size_t ws_size,
                              hipStream_t stream) {
  const float* x       = (const float*)d_in[0];
  const int*   edge    = (const int*)d_in[1];
  const int*   node_id = (const int*)d_in[2];
  const float* W_gcn   = (const float*)d_in[3];
  const float* b_gcn   = (const float*)d_in[4];
  const float* W1      = (const float*)d_in[5];
  const float* b1      = (const float*)d_in[6];
  const float* W2      = (const float*)d_in[7];
  const float* b2      = (const float*)d_in[8];
  float* out = (float*)d_out;

  int N = in_sizes[0] / IN_FEATS;
  int E = in_sizes[1] / 2;
  const int* erow = edge;
  const int* ecol = edge + E;
  int nbins = (N + 255) >> 8;           // 196 for N=50000 (<=256 required)
  int NB = (E + EPB - 1) / EPB;         // 196 binning blocks (<=256 required)

  char* ws = (char*)d_ws;
  size_t off = 0;
  auto alloc = [&](size_t bytes) {
    char* p = ws + off;
    off = (off + bytes + 255) & ~(size_t)255;
    return p;
  };
  __hip_bfloat16* xwd = (__hip_bfloat16*)alloc((size_t)N * ENC_H * sizeof(__hip_bfloat16));
  float* enc  = (float*)alloc((size_t)N * ENC_H * sizeof(float));
  float* dinv = (float*)alloc((size_t)N * sizeof(float));
  int*  nstart = (int*)alloc((size_t)(N + 1) * sizeof(int));
  unsigned int*   binned   = (unsigned int*)alloc((size_t)E * sizeof(unsigned int));
  int*            einv     = (int*)alloc((size_t)E * sizeof(int));
  unsigned short* sorted_r = (unsigned short*)alloc((size_t)E * sizeof(unsigned short));
  int* bbc      = (int*)alloc((size_t)NB * nbins * sizeof(int));
  int* base     = (int*)alloc((size_t)NB * nbins * sizeof(int));
  int* binTot   = (int*)alloc((size_t)nbins * sizeof(int));
  int* binStart = (int*)alloc((size_t)(nbins + 1) * sizeof(int));
  __hip_bfloat16* P1 = (__hip_bfloat16*)alloc((size_t)N * 32 * sizeof(__hip_bfloat16));
  __hip_bfloat16* P2 = (__hip_bfloat16*)alloc((size_t)N * 32 * sizeof(__hip_bfloat16));
  __hip_bfloat16* Q1 = (__hip_bfloat16*)alloc((size_t)N * 32 * sizeof(__hip_bfloat16));
  __hip_bfloat16* Q2 = (__hip_bfloat16*)alloc((size_t)N * 32 * sizeof(__hip_bfloat16));
  __hip_bfloat16* partial = (__hip_bfloat16*)alloc((size_t)E * sizeof(__hip_bfloat16));
  float* t3   = (float*)alloc((size_t)DEC_H * sizeof(float));
  (void)ws_size; (void)n_in; (void)out_size;

  const int B = 256;
  int ge  = (E + B - 1) / B;
  int gxw = (N * 4 + B - 1) / B;
  int gg  = (N * 5 + B - 1) / B;
  int gpq = (N * DEC_H + B - 1) / B;

  k_binhist   <<<NB, 1024, 0, stream>>>(ecol, bbc, E, nbins);
  k_colA      <<<nbins, 256, 0, stream>>>(bbc, base, binTot, NB, nbins);
  k_colB      <<<1, 256, 0, stream>>>(binTot, binStart, nbins);
  k_binscatter<<<NB, 1024, 0, stream>>>(erow, ecol, base, binStart, binned, einv, E, nbins);
  k_binsort   <<<nbins, 1024, 0, stream>>>(binned, binStart, sorted_r, nstart, dinv, N, E);
  k_xw        <<<gxw, B, 0, stream>>>(x, W_gcn, dinv, xwd, N);
  k_gather    <<<gg, B, 0, stream>>>(nstart, sorted_r, xwd, dinv, b_gcn, enc, N);
  k_pq        <<<gpq, B, 0, stream>>>(enc, W1, P1, P2, Q1, Q2, N);
  k_t3        <<<1, DEC_H, 0, stream>>>(enc, W1, b1, node_id, t3);
  k_dec_half<0><<<ge, B, 0, stream>>>(binned, P1, Q1, t3, W2, b2, partial, E);
  k_dec_half<1><<<ge, B, 0, stream>>>(binned, P2, Q2, t3, W2, b2, partial, E);
  k_final     <<<ge, B, 0, stream>>>(einv, partial, out, E);
}

// Round 16
// 171.297 us; speedup vs baseline: 1.5168x; 1.0080x over previous
//
#include <hip/hip_runtime.h>
#include <hip/hip_bf16.h>

#define IN_FEATS 256
#define ENC_H    20
#define DEC_H    64
#define EPB      8192    // edges per binning block

#define NT_LOAD(x) __builtin_nontemporal_load(&(x))

// ---------------- threefry2x32 (JAX-compatible) ----------------
__device__ __forceinline__ unsigned int rotl32(unsigned int x, int d) {
  return (x << d) | (x >> (32 - d));
}

__device__ __forceinline__ void threefry2x32(unsigned int k0, unsigned int k1,
                                             unsigned int x0, unsigned int x1,
                                             unsigned int& o0, unsigned int& o1) {
  unsigned int ks0 = k0, ks1 = k1, ks2 = k0 ^ k1 ^ 0x1BD11BDAu;
  x0 += ks0; x1 += ks1;
  x0 += x1; x1 = rotl32(x1, 13); x1 ^= x0;
  x0 += x1; x1 = rotl32(x1, 15); x1 ^= x0;
  x0 += x1; x1 = rotl32(x1, 26); x1 ^= x0;
  x0 += x1; x1 = rotl32(x1,  6); x1 ^= x0;
  x0 += ks1; x1 += ks2 + 1u;
  x0 += x1; x1 = rotl32(x1, 17); x1 ^= x0;
  x0 += x1; x1 = rotl32(x1, 29); x1 ^= x0;
  x0 += x1; x1 = rotl32(x1, 16); x1 ^= x0;
  x0 += x1; x1 = rotl32(x1, 24); x1 ^= x0;
  x0 += ks2; x1 += ks0 + 2u;
  x0 += x1; x1 = rotl32(x1, 13); x1 ^= x0;
  x0 += x1; x1 = rotl32(x1, 15); x1 ^= x0;
  x0 += x1; x1 = rotl32(x1, 26); x1 ^= x0;
  x0 += x1; x1 = rotl32(x1,  6); x1 ^= x0;
  x0 += ks0; x1 += ks1 + 3u;
  x0 += x1; x1 = rotl32(x1, 17); x1 ^= x0;
  x0 += x1; x1 = rotl32(x1, 29); x1 ^= x0;
  x0 += x1; x1 = rotl32(x1, 16); x1 ^= x0;
  x0 += x1; x1 = rotl32(x1, 24); x1 ^= x0;
  x0 += ks1; x1 += ks2 + 4u;
  x0 += x1; x1 = rotl32(x1, 13); x1 ^= x0;
  x0 += x1; x1 = rotl32(x1, 15); x1 ^= x0;
  x0 += x1; x1 = rotl32(x1, 26); x1 ^= x0;
  x0 += x1; x1 = rotl32(x1,  6); x1 ^= x0;
  x0 += ks2; x1 += ks0 + 5u;
  o0 = x0; o1 = x1;
}

__device__ __forceinline__ float2 bf2_unpack(unsigned int u) {
  float2 f;
  f.x = __uint_as_float(u << 16);
  f.y = __uint_as_float(u & 0xffff0000u);
  return f;
}

// ---------------- binning + sort (no global atomics anywhere) ----------------

// per-(block,bin) histogram of col>>8
__global__ __launch_bounds__(1024) void k_binhist(const int* __restrict__ col,
                                                  int* __restrict__ bbc, int E, int nbins) {
  __shared__ int h[256];
  int t = threadIdx.x;
  if (t < 256) h[t] = 0;
  __syncthreads();
  int lo = blockIdx.x * EPB;
  int hi = min(lo + EPB, E);
  for (int e = lo + t; e < hi; e += 1024) atomicAdd(&h[col[e] >> 8], 1);
  __syncthreads();
  if (t < nbins) bbc[blockIdx.x * nbins + t] = h[t];
}

// colA: per-bin scan over the block axis (parallel across blocks' counts)
__global__ void k_colA(const int* __restrict__ bbc, int* __restrict__ base,
                       int* __restrict__ binTot, int nblk, int nbins) {
  __shared__ int sd[256];
  int t = threadIdx.x;
  int bin = blockIdx.x;
  int v = (t < nblk) ? bbc[(size_t)t * nbins + bin] : 0;
  sd[t] = v;
  __syncthreads();
#pragma unroll
  for (int off = 1; off < 256; off <<= 1) {
    int tmp = (t >= off) ? sd[t - off] : 0;
    __syncthreads();
    sd[t] += tmp;
    __syncthreads();
  }
  if (t < nblk) base[(size_t)t * nbins + bin] = sd[t] - v;  // exclusive, bin-local
  if (t == 255) binTot[bin] = sd[255];
}

// colB: single block scans <=256 bin totals -> binStart[nbins+1]
__global__ void k_colB(const int* __restrict__ binTot, int* __restrict__ binStart, int nbins) {
  __shared__ int sd[256];
  int t = threadIdx.x;
  int v = (t < nbins) ? binTot[t] : 0;
  sd[t] = v;
  __syncthreads();
#pragma unroll
  for (int off = 1; off < 256; off <<= 1) {
    int tmp = (t >= off) ? sd[t - off] : 0;
    __syncthreads();
    sd[t] += tmp;
    __syncthreads();
  }
  if (t < nbins) {
    binStart[t] = sd[t] - v;
    if (t == nbins - 1) binStart[nbins] = sd[t];
  }
}

// scatter edges into bins: binned[slot] = r | c<<16 ; einv[e] = slot (coalesced)
__global__ __launch_bounds__(1024) void k_binscatter(const int* __restrict__ row,
                                                     const int* __restrict__ col,
                                                     const int* __restrict__ base,
                                                     const int* __restrict__ binStart,
                                                     unsigned int* __restrict__ binned,
                                                     int* __restrict__ einv,
                                                     int E, int nbins) {
  __shared__ int cur[256];
  int t = threadIdx.x;
  if (t < nbins) cur[t] = binStart[t] + base[(size_t)blockIdx.x * nbins + t];
  __syncthreads();
  int lo = blockIdx.x * EPB;
  int hi = min(lo + EPB, E);
  for (int e = lo + t; e < hi; e += 1024) {
    int c = col[e];
    int slot = atomicAdd(&cur[c >> 8], 1);
    binned[slot] = (unsigned int)row[e] | ((unsigned int)c << 16);
    einv[e] = slot;
  }
}

// per-bin counting sort by node: emits sorted_r[] (u16), nstart[N+1], dinv[N]
__global__ __launch_bounds__(1024) void k_binsort(const unsigned int* __restrict__ binned,
                                                  const int* __restrict__ binStart,
                                                  unsigned short* __restrict__ sorted_r,
                                                  int* __restrict__ nstart,
                                                  float* __restrict__ dinv,
                                                  int N, int E) {
  __shared__ int cnt[256];
  __shared__ int ls[256];
  __shared__ int cur[256];
  int t = threadIdx.x;
  int bin = blockIdx.x;
  if (t < 256) cnt[t] = 0;
  __syncthreads();
  int s = binStart[bin], epos = binStart[bin + 1];
  for (int i = s + t; i < epos; i += 1024)
    atomicAdd(&cnt[(binned[i] >> 16) & 0xFFu], 1);
  __syncthreads();
  int v = (t < 256) ? cnt[t] : 0;
  if (t < 256) ls[t] = v;
  __syncthreads();
#pragma unroll
  for (int off = 1; off < 256; off <<= 1) {
    int tmp = 0;
    if (t < 256 && t >= off) tmp = ls[t - off];
    __syncthreads();
    if (t < 256 && t >= off) ls[t] += tmp;
    __syncthreads();
  }
  if (t < 256) {
    int ex = ls[t] - v;      // exclusive prefix within bin
    cur[t] = s + ex;
    int n = (bin << 8) + t;
    if (n < N) {
      nstart[n] = s + ex;
      dinv[n] = rsqrtf((float)(v + 1));
    }
  }
  if (bin == 0 && t == 0) nstart[N] = E;
  __syncthreads();
  for (int i = s + t; i < epos; i += 1024) {
    unsigned int e32 = binned[i];
    int cl = (int)((e32 >> 16) & 0xFFu);
    int slot = atomicAdd(&cur[cl], 1);
    sorted_r[slot] = (unsigned short)(e32 & 0xFFFFu);
  }
}

// ---------------- dense kernels ----------------

// xwd[n] = bf16((x[n] @ W_gcn) * dinv[n]); 4 threads/node, interleaved float4 access
__global__ void k_xw(const float* __restrict__ x, const float* __restrict__ W,
                     const float* __restrict__ dinv, __hip_bfloat16* __restrict__ xwd, int N) {
  __shared__ float Wl[IN_FEATS * ENC_H];
  for (int i = threadIdx.x; i < IN_FEATS * ENC_H; i += blockDim.x) Wl[i] = W[i];
  __syncthreads();
  int g = blockIdx.x * blockDim.x + threadIdx.x;
  int n = g >> 2, part = g & 3;
  if (n >= N) return;
  float acc[ENC_H];
#pragma unroll
  for (int j = 0; j < ENC_H; j++) acc[j] = 0.0f;
  const float4* x4 = reinterpret_cast<const float4*>(x + (size_t)n * IN_FEATS);
#pragma unroll 4
  for (int k4 = 0; k4 < 16; k4++) {
    float4 v = x4[k4 * 4 + part];
    int kbase = k4 * 16 + part * 4;
    const float* w0 = &Wl[(kbase + 0) * ENC_H];
    const float* w1 = &Wl[(kbase + 1) * ENC_H];
    const float* w2 = &Wl[(kbase + 2) * ENC_H];
    const float* w3 = &Wl[(kbase + 3) * ENC_H];
#pragma unroll
    for (int j = 0; j < ENC_H; j++) {
      acc[j] = fmaf(v.x, w0[j], acc[j]);
      acc[j] = fmaf(v.y, w1[j], acc[j]);
      acc[j] = fmaf(v.z, w2[j], acc[j]);
      acc[j] = fmaf(v.w, w3[j], acc[j]);
    }
  }
#pragma unroll
  for (int j = 0; j < ENC_H; j++) acc[j] += __shfl_xor(acc[j], 1);
#pragma unroll
  for (int j = 0; j < ENC_H; j++) acc[j] += __shfl_xor(acc[j], 2);
  float d = dinv[n];
  __hip_bfloat16* o = xwd + (size_t)n * ENC_H;
  int jb = part * 5;
#pragma unroll
  for (int jj = 0; jj < 5; jj++) o[jb + jj] = __float2bfloat16(acc[jb + jj] * d);
}

// enc: 5 lanes/node, each lane owns 4 feats, uint2 (4 bf16) per neighbor
__global__ void k_gather(const int* __restrict__ nstart,
                         const unsigned short* __restrict__ sorted_r,
                         const __hip_bfloat16* __restrict__ xwd, const float* __restrict__ dinv,
                         const float* __restrict__ bg, float* __restrict__ enc, int N) {
  int t = blockIdx.x * blockDim.x + threadIdx.x;
  int n = t / 5;
  int lane5 = t - n * 5;
  if (n >= N) return;
  int jb = lane5 * 4;
  const char* xwb = (const char*)xwd;
  // self loop
  uint2 sv = *reinterpret_cast<const uint2*>(xwb + (size_t)n * 40 + lane5 * 8);
  float2 a01 = bf2_unpack(sv.x), a23 = bf2_unpack(sv.y);
  float f0 = a01.x, f1 = a01.y, f2 = a23.x, f3 = a23.y;
  int s = nstart[n], epos = nstart[n + 1];
  for (int k = s; k < epos; k++) {
    int r = (int)sorted_r[k];
    uint2 v = *reinterpret_cast<const uint2*>(xwb + (size_t)r * 40 + lane5 * 8);
    float2 b01 = bf2_unpack(v.x), b23 = bf2_unpack(v.y);
    f0 += b01.x; f1 += b01.y; f2 += b23.x; f3 += b23.y;
  }
  float d = dinv[n];
  float4 o;
  o.x = fmaxf(f0 * d + bg[jb + 0], 0.0f);
  o.y = fmaxf(f1 * d + bg[jb + 1], 0.0f);
  o.z = fmaxf(f2 * d + bg[jb + 2], 0.0f);
  o.w = fmaxf(f3 * d + bg[jb + 3], 0.0f);
  *reinterpret_cast<float4*>(enc + (size_t)n * ENC_H + jb) = o;
}

// P/Q split in j-halves + fused t3 (block 0): t3 = enc[node_id] @ W1[40:60] + b1
__global__ void k_pq(const float* __restrict__ enc, const float* __restrict__ W1,
                     const float* __restrict__ b1, const int* __restrict__ node_id,
                     __hip_bfloat16* __restrict__ P1, __hip_bfloat16* __restrict__ P2,
                     __hip_bfloat16* __restrict__ Q1, __hip_bfloat16* __restrict__ Q2,
                     float* __restrict__ t3, int N) {
  __shared__ float Wl[2 * ENC_H * DEC_H];
  for (int i = threadIdx.x; i < 2 * ENC_H * DEC_H; i += blockDim.x) Wl[i] = W1[i];
  __syncthreads();
  int t = blockIdx.x * blockDim.x + threadIdx.x;
  if (blockIdx.x == 0 && threadIdx.x < DEC_H) {
    int j = threadIdx.x;
    int nid = node_id[0];
    const float* en = enc + (size_t)nid * ENC_H;
    float a = b1[j];
#pragma unroll
    for (int k = 0; k < ENC_H; k++) a = fmaf(en[k], W1[(2 * ENC_H + k) * DEC_H + j], a);
    t3[j] = a;
  }
  int n = t / DEC_H, j = t % DEC_H;
  if (n >= N) return;
  const float* en = enc + (size_t)n * ENC_H;
  float p = 0.0f, q = 0.0f;
#pragma unroll
  for (int k = 0; k < ENC_H; k++) {
    float ev = en[k];
    p = fmaf(ev, Wl[k * DEC_H + j], p);
    q = fmaf(ev, Wl[(k + ENC_H) * DEC_H + j], q);
  }
  size_t idx = (size_t)n * 32 + (j & 31);
  if (j < 32) { P1[idx] = __float2bfloat16(p); Q1[idx] = __float2bfloat16(q); }
  else        { P2[idx] = __float2bfloat16(p); Q2[idx] = __float2bfloat16(q); }
}

// decoder half-pass: HALF=0 writes bf16 partial; HALF=1 accumulates and writes bf16 od
template <int HALF>
__global__ void k_dec_half(const unsigned int* __restrict__ binned,
                           const __hip_bfloat16* __restrict__ Ph,
                           const __hip_bfloat16* __restrict__ Qh,
                           const float* __restrict__ t3, const float* __restrict__ W2,
                           const float* __restrict__ b2,
                           __hip_bfloat16* __restrict__ partial, int E) {
  __shared__ float t3l[32], w2l[32];
  if (threadIdx.x < 32) {
    t3l[threadIdx.x] = t3[HALF * 32 + threadIdx.x];
    w2l[threadIdx.x] = W2[HALF * 32 + threadIdx.x];
  }
  __syncthreads();
  int pos = blockIdx.x * blockDim.x + threadIdx.x;
  if (pos >= E) return;
  unsigned int v = NT_LOAD(binned[pos]);   // single-use stream: don't evict P/Q
  int r = (int)(v & 0xFFFFu);
  int c = (int)(v >> 16);
  const uint4* pr = reinterpret_cast<const uint4*>(Ph + (size_t)r * 32);  // 64B row
  const uint4* qc = reinterpret_cast<const uint4*>(Qh + (size_t)c * 32);
  float acc = 0.0f;
#pragma unroll
  for (int b = 0; b < 4; b++) {  // 8 bf16 per uint4
    uint4 pu = pr[b];
    uint4 qu = qc[b];
    int j0 = b * 8;
    float2 p0 = bf2_unpack(pu.x), q0 = bf2_unpack(qu.x);
    float2 p1 = bf2_unpack(pu.y), q1 = bf2_unpack(qu.y);
    float2 p2 = bf2_unpack(pu.z), q2 = bf2_unpack(qu.z);
    float2 p3 = bf2_unpack(pu.w), q3 = bf2_unpack(qu.w);
    float h;
    h = fmaxf(p0.x + q0.x + t3l[j0 + 0], 0.0f); acc = fmaf(h, w2l[j0 + 0], acc);
    h = fmaxf(p0.y + q0.y + t3l[j0 + 1], 0.0f); acc = fmaf(h, w2l[j0 + 1], acc);
    h = fmaxf(p1.x + q1.x + t3l[j0 + 2], 0.0f); acc = fmaf(h, w2l[j0 + 2], acc);
    h = fmaxf(p1.y + q1.y + t3l[j0 + 3], 0.0f); acc = fmaf(h, w2l[j0 + 3], acc);
    h = fmaxf(p2.x + q2.x + t3l[j0 + 4], 0.0f); acc = fmaf(h, w2l[j0 + 4], acc);
    h = fmaxf(p2.y + q2.y + t3l[j0 + 5], 0.0f); acc = fmaf(h, w2l[j0 + 5], acc);
    h = fmaxf(p3.x + q3.x + t3l[j0 + 6], 0.0f); acc = fmaf(h, w2l[j0 + 6], acc);
    h = fmaxf(p3.y + q3.y + t3l[j0 + 7], 0.0f); acc = fmaf(h, w2l[j0 + 7], acc);
  }
  if (HALF == 0) {
    partial[pos] = __float2bfloat16(acc);
  } else {
    float od = acc + __bfloat162float(partial[pos]) + b2[0];
    partial[pos] = __float2bfloat16(od);  // sequential RMW, coalesced
  }
}

// final: e in order -> od gather from L2-resident bf16 partial, gumbel-sigmoid, sequential out
__global__ void k_final(const int* __restrict__ einv, const __hip_bfloat16* __restrict__ partial,
                        float* __restrict__ out, int E) {
  int e = blockIdx.x * blockDim.x + threadIdx.x;
  if (e >= E) return;
  float od = __bfloat162float(partial[NT_LOAD(einv[e])]);  // einv single-use stream
  unsigned int o0, o1;
  threefry2x32(0u, 123u, 0u, (unsigned int)e, o0, o1);
  unsigned int bits = o0 ^ o1;
  float u = __uint_as_float((bits >> 9) | 0x3f800000u) - 1.0f;
  float eps = (-0.9998f) * u + 0.9999f;
  float gate = logf(eps) - log1pf(-eps);
  float s = 1.0f / (1.0f + expf(-(gate + od)));
  out[e] = s;
}

// ---------------- launch ----------------
extern "C" void kernel_launch(void* const* d_in, const int* in_sizes, int n_in,
                              void* d_out, int out_size, void* d_ws, size_t ws_size,
                              hipStream_t stream) {
  const float* x       = (const float*)d_in[0];
  const int*   edge    = (const int*)d_in[1];
  const int*   node_id = (const int*)d_in[2];
  const float* W_gcn   = (const float*)d_in[3];
  const float* b_gcn   = (const float*)d_in[4];
  const float* W1      = (const float*)d_in[5];
  const float* b1      = (const float*)d_in[6];
  const float* W2      = (const float*)d_in[7];
  const float* b2      = (const float*)d_in[8];
  float* out = (float*)d_out;

  int N = in_sizes[0] / IN_FEATS;
  int E = in_sizes[1] / 2;
  const int* erow = edge;
  const int* ecol = edge + E;
  int nbins = (N + 255) >> 8;           // 196 for N=50000 (<=256 required)
  int NB = (E + EPB - 1) / EPB;         // 196 binning blocks (<=256 required)

  char* ws = (char*)d_ws;
  size_t off = 0;
  auto alloc = [&](size_t bytes) {
    char* p = ws + off;
    off = (off + bytes + 255) & ~(size_t)255;
    return p;
  };
  __hip_bfloat16* xwd = (__hip_bfloat16*)alloc((size_t)N * ENC_H * sizeof(__hip_bfloat16));
  float* enc  = (float*)alloc((size_t)N * ENC_H * sizeof(float));
  float* dinv = (float*)alloc((size_t)N * sizeof(float));
  int*  nstart = (int*)alloc((size_t)(N + 1) * sizeof(int));
  unsigned int*   binned   = (unsigned int*)alloc((size_t)E * sizeof(unsigned int));
  int*            einv     = (int*)alloc((size_t)E * sizeof(int));
  unsigned short* sorted_r = (unsigned short*)alloc((size_t)E * sizeof(unsigned short));
  int* bbc      = (int*)alloc((size_t)NB * nbins * sizeof(int));
  int* base     = (int*)alloc((size_t)NB * nbins * sizeof(int));
  int* binTot   = (int*)alloc((size_t)nbins * sizeof(int));
  int* binStart = (int*)alloc((size_t)(nbins + 1) * sizeof(int));
  __hip_bfloat16* P1 = (__hip_bfloat16*)alloc((size_t)N * 32 * sizeof(__hip_bfloat16));
  __hip_bfloat16* P2 = (__hip_bfloat16*)alloc((size_t)N * 32 * sizeof(__hip_bfloat16));
  __hip_bfloat16* Q1 = (__hip_bfloat16*)alloc((size_t)N * 32 * sizeof(__hip_bfloat16));
  __hip_bfloat16* Q2 = (__hip_bfloat16*)alloc((size_t)N * 32 * sizeof(__hip_bfloat16));
  __hip_bfloat16* partial = (__hip_bfloat16*)alloc((size_t)E * sizeof(__hip_bfloat16));
  float* t3   = (float*)alloc((size_t)DEC_H * sizeof(float));
  (void)ws_size; (void)n_in; (void)out_size;

  const int B = 256;
  int ge  = (E + B - 1) / B;
  int gxw = (N * 4 + B - 1) / B;
  int gg  = (N * 5 + B - 1) / B;
  int gpq = (N * DEC_H + B - 1) / B;

  k_binhist   <<<NB, 1024, 0, stream>>>(ecol, bbc, E, nbins);
  k_colA      <<<nbins, 256, 0, stream>>>(bbc, base, binTot, NB, nbins);
  k_colB      <<<1, 256, 0, stream>>>(binTot, binStart, nbins);
  k_binscatter<<<NB, 1024, 0, stream>>>(erow, ecol, base, binStart, binned, einv, E, nbins);
  k_binsort   <<<nbins, 1024, 0, stream>>>(binned, binStart, sorted_r, nstart, dinv, N, E);
  k_xw        <<<gxw, B, 0, stream>>>(x, W_gcn, dinv, xwd, N);
  k_gather    <<<gg, B, 0, stream>>>(nstart, sorted_r, xwd, dinv, b_gcn, enc, N);
  k_pq        <<<gpq, B, 0, stream>>>(enc, W1, b1, node_id, P1, P2, Q1, Q2, t3, N);
  k_dec_half<0><<<ge, B, 0, stream>>>(binned, P1, Q1, t3, W2, b2, partial, E);
  k_dec_half<1><<<ge, B, 0, stream>>>(binned, P2, Q2, t3, W2, b2, partial, E);
  k_final     <<<ge, B, 0, stream>>>(einv, partial, out, E);
}